// Round 1
// baseline (382.145 us; speedup 1.0000x reference)
//
#include <hip/hip_runtime.h>
#include <hip/hip_bf16.h>

#define L_ 8
#define M_ 128
#define K_ 32
#define D_ 16
#define B_ 2048
#define N_ 1024           // L_*M_
#define SLAB_ 32768       // B_*D_ == D_*B_ elements per node slab

// ---------------------------------------------------------------------------
// Transpose one or more (B_, D_) slabs into (D_, B_) layout.
// grid.x = num_slabs * 32  (32 b-tiles of 64 b each), block = 256 threads.
// ---------------------------------------------------------------------------
__global__ __launch_bounds__(256) void transpose_bd(const float* __restrict__ src,
                                                    float* __restrict__ dst) {
    int blk = blockIdx.x;
    int n   = blk >> 5;       // slab index
    int bt  = blk & 31;       // b-tile
    int b0  = bt * 64;

    __shared__ float lds[D_][68];   // row stride 68 floats = 272 B (16B-aligned rows)

    int tid = threadIdx.x;

    // Load: 64 b x 16 d = 1024 floats = 256 float4, coalesced.
    const float4* s4 = (const float4*)(src + (size_t)n * SLAB_);
    int b  = tid >> 2;        // 0..63 within tile
    int dq = tid & 3;         // which float4 along d
    float4 v = s4[(size_t)(b0 + b) * 4 + dq];
    lds[dq * 4 + 0][b] = v.x;
    lds[dq * 4 + 1][b] = v.y;
    lds[dq * 4 + 2][b] = v.z;
    lds[dq * 4 + 3][b] = v.w;
    __syncthreads();

    // Store: 16 d rows x 64 b = 256 float4 along b, coalesced.
    int d  = tid >> 4;        // 0..15
    int bq = tid & 15;        // 0..15 -> float4 index along b
    float4 w;
    w.x = lds[d][bq * 4 + 0];
    w.y = lds[d][bq * 4 + 1];
    w.z = lds[d][bq * 4 + 2];
    w.w = lds[d][bq * 4 + 3];
    float4* d4 = (float4*)(dst + (size_t)n * SLAB_ + (size_t)d * B_ + b0);
    d4[bq] = w;
}

// ---------------------------------------------------------------------------
// One layer. grid.x = M_ * 8 (8 b-tiles of 256), block = 256 (1 thread per b).
// Buffers are stride-parametric: value(node_slab, f, b) = buf[slab*SLAB_ + f*fs + b*bs].
//   transposed: fs = B_, bs = 1   |   native: fs = 1, bs = D_
// ---------------------------------------------------------------------------
__global__ __launch_bounds__(256) void layer_kernel(
    int l,
    const float* __restrict__ xbuf, int xfs, int xbs,
    const float* __restrict__ tbuf, int tfs, int tbs,
    const float* __restrict__ obuf, int ofs, int obs,
    const int* __restrict__ sn, const int* __restrict__ sf,
    const float* __restrict__ W, const float* __restrict__ bias,
    float* __restrict__ out, float* __restrict__ outT, int writeT)
{
    int m  = blockIdx.x >> 3;
    int bt = blockIdx.x & 7;
    int n  = l * M_ + m;
    int b  = bt * 256 + threadIdx.x;

    __shared__ float        Wsh[D_][K_];
    __shared__ float        bsh[D_];
    __shared__ const float* colp[K_];
    __shared__ int          colbs[K_];

    int tid = threadIdx.x;

    // W_n: 16x32 = 512 floats = 128 float4
    if (tid < 128) {
        ((float4*)&Wsh[0][0])[tid] = ((const float4*)(W + (size_t)n * D_ * K_))[tid];
    }
    if (tid < D_) bsh[tid] = bias[(size_t)n * D_ + tid];
    if (tid < K_) {
        int s = sn[(size_t)n * K_ + tid];
        int f = sf[(size_t)n * K_ + tid];
        const float* p;
        int bs;
        if (s == 0) {                      // source is x
            p  = xbuf + (size_t)f * xfs;
            bs = xbs;
        } else {
            int ls = (s - 1) >> 7;         // source node's layer
            if (ls >= l) {                 // not yet computed -> trace (stop-grad)
                p  = tbuf + (size_t)(s - 1) * SLAB_ + (size_t)f * tfs;
                bs = tbs;
            } else {                       // previously computed output
                p  = obuf + (size_t)(s - 1) * SLAB_ + (size_t)f * ofs;
                bs = obs;
            }
        }
        colp[tid]  = p;
        colbs[tid] = bs;
    }
    __syncthreads();

    // Gather K_ values for this b (coalesced when bs == 1).
    float g[K_];
#pragma unroll
    for (int k = 0; k < K_; ++k) {
        g[k] = colp[k][(size_t)b * colbs[k]];
    }

    // o[d] = relu(bias[d] + sum_k g[k] * W[d][k])
    float4 o4[4];
    float* o = (float*)o4;
#pragma unroll
    for (int d = 0; d < D_; ++d) {
        float acc = bsh[d];
#pragma unroll
        for (int k = 0; k < K_; ++k) acc = fmaf(g[k], Wsh[d][k], acc);
        acc = fmaxf(acc, 0.0f);
        o[d] = acc;
        if (writeT) outT[(size_t)n * SLAB_ + (size_t)d * B_ + b] = acc;
    }

    // d_out native layout: out[n, b, d] -> 64B contiguous per thread.
    float4* op = (float4*)(out + (size_t)n * SLAB_ + (size_t)b * D_);
    op[0] = o4[0];
    op[1] = o4[1];
    op[2] = o4[2];
    op[3] = o4[3];
}

extern "C" void kernel_launch(void* const* d_in, const int* in_sizes, int n_in,
                              void* d_out, int out_size, void* d_ws, size_t ws_size,
                              hipStream_t stream) {
    const float* x     = (const float*)d_in[0];
    const float* trace = (const float*)d_in[1];
    const int*   sn    = (const int*)d_in[2];
    const int*   sf    = (const int*)d_in[3];
    const float* W     = (const float*)d_in[4];
    const float* bias  = (const float*)d_in[5];
    float*       out   = (float*)d_out;

    const size_t xT_elems  = (size_t)D_ * B_;        // 32768
    const size_t big_elems = (size_t)N_ * SLAB_;     // 33554432
    const size_t needA = sizeof(float) * (xT_elems + 2 * big_elems); // ~269 MB
    const size_t needB = sizeof(float) * (xT_elems + 1 * big_elems); // ~134 MB

    float* ws = (float*)d_ws;

    if (ws_size >= needA) {
        // Tier A: fully transposed working set.
        float* xT     = ws;
        float* traceT = ws + xT_elems;
        float* outT   = traceT + big_elems;

        transpose_bd<<<32, 256, 0, stream>>>(x, xT);
        transpose_bd<<<N_ * 32, 256, 0, stream>>>(trace, traceT);
        for (int l = 0; l < L_; ++l) {
            layer_kernel<<<M_ * 8, 256, 0, stream>>>(
                l,
                xT,     B_, 1,
                traceT, B_, 1,
                outT,   B_, 1,
                sn, sf, W, bias, out, outT, 1);
        }
    } else if (ws_size >= needB) {
        // Tier B: transpose x + trace only; outputs gathered from d_out (strided).
        float* xT     = ws;
        float* traceT = ws + xT_elems;

        transpose_bd<<<32, 256, 0, stream>>>(x, xT);
        transpose_bd<<<N_ * 32, 256, 0, stream>>>(trace, traceT);
        for (int l = 0; l < L_; ++l) {
            layer_kernel<<<M_ * 8, 256, 0, stream>>>(
                l,
                xT,     B_, 1,
                traceT, B_, 1,
                out,    1,  D_,
                sn, sf, W, bias, out, nullptr, 0);
        }
    } else {
        // Tier C: no workspace — all native-layout (strided) gathers. Correct, slow.
        for (int l = 0; l < L_; ++l) {
            layer_kernel<<<M_ * 8, 256, 0, stream>>>(
                l,
                x,     1, D_,
                trace, 1, D_,
                out,   1, D_,
                sn, sf, W, bias, out, nullptr, 0);
        }
    }
}

// Round 2
// 366.694 us; speedup vs baseline: 1.0421x; 1.0421x over previous
//
#include <hip/hip_runtime.h>
#include <hip/hip_bf16.h>

#define L_ 8
#define M_ 128
#define K_ 32
#define D_ 16
#define B_ 2048
#define N_ 1024           // L_*M_
#define SLAB_ 32768       // B_*D_ == D_*B_ elements per node slab

// ---------------------------------------------------------------------------
// Transpose (B_, D_) slabs into (D_, B_) layout. Fused: blocks [0, N_*32)
// handle trace slabs; blocks [N_*32, N_*32+32) handle x.
// block = 256 threads; each block does one 64b x 16d tile.
// LDS row stride 65 floats: write bank = (17.. see notes) <=2-way, read
// bank = (d + 4*bq + r) % 32 -> distinct over 32 lanes, 2-way over 64. Free.
// ---------------------------------------------------------------------------
__global__ __launch_bounds__(256) void transpose_bd(const float* __restrict__ trace,
                                                    const float* __restrict__ x,
                                                    float* __restrict__ traceT,
                                                    float* __restrict__ xT) {
    int blk = blockIdx.x;
    const float* src;
    float* dst;
    int bt;
    if (blk < N_ * 32) {
        int n = blk >> 5;
        src = trace + (size_t)n * SLAB_;
        dst = traceT + (size_t)n * SLAB_;
        bt  = blk & 31;
    } else {
        src = x;
        dst = xT;
        bt  = blk - N_ * 32;
    }
    int b0 = bt * 64;

    __shared__ float lds[D_][65];

    int tid = threadIdx.x;

    // Load: 64 b x 16 d = 256 float4, fully coalesced (4 KB contiguous).
    const float4* s4 = (const float4*)src;
    int b  = tid >> 2;        // 0..63 within tile
    int dq = tid & 3;         // which float4 along d
    float4 v = s4[(size_t)(b0 + b) * 4 + dq];
    lds[dq * 4 + 0][b] = v.x;
    lds[dq * 4 + 1][b] = v.y;
    lds[dq * 4 + 2][b] = v.z;
    lds[dq * 4 + 3][b] = v.w;
    __syncthreads();

    // Store: 16 d rows x 64 b, coalesced 256 B chunks.
    int d  = tid >> 4;        // 0..15
    int bq = tid & 15;        // float4 index along b
    float4 w;
    w.x = lds[d][bq * 4 + 0];
    w.y = lds[d][bq * 4 + 1];
    w.z = lds[d][bq * 4 + 2];
    w.w = lds[d][bq * 4 + 3];
    ((float4*)(dst + (size_t)d * B_ + b0))[bq] = w;
}

// ---------------------------------------------------------------------------
// One layer. grid.x = M_ * 8 (8 b-tiles of 256), block = 256 (1 thread per b).
// Stride-parametric sources: value(slab, f, b) = buf[slab*SLAB_ + f*fs + b*bs].
// Native d_out store is staged through LDS so each wave-store is 4 KB
// unit-stride (the direct per-thread float4 store is 64 B lane-strided ->
// 64 lines per instruction, 16x request amplification).
// ---------------------------------------------------------------------------
__global__ __launch_bounds__(256) void layer_kernel(
    int l,
    const float* __restrict__ xbuf, int xfs, int xbs,
    const float* __restrict__ tbuf, int tfs, int tbs,
    const float* __restrict__ obuf, int ofs, int obs,
    const int* __restrict__ sn, const int* __restrict__ sf,
    const float* __restrict__ W, const float* __restrict__ bias,
    float* __restrict__ out, float* __restrict__ outT, int writeT)
{
    int m  = blockIdx.x >> 3;
    int bt = blockIdx.x & 7;
    int n  = l * M_ + m;
    int b  = bt * 256 + threadIdx.x;

    __shared__ float        Wsh[D_][K_];
    __shared__ float        bsh[D_];
    __shared__ const float* colp[K_];
    __shared__ int          colbs[K_];
    __shared__ float        osh[256][17];   // stride 17: <=2-way banks both phases

    int tid = threadIdx.x;

    // W_n: 16x32 = 512 floats = 128 float4
    if (tid < 128) {
        ((float4*)&Wsh[0][0])[tid] = ((const float4*)(W + (size_t)n * D_ * K_))[tid];
    }
    if (tid < D_) bsh[tid] = bias[(size_t)n * D_ + tid];
    if (tid < K_) {
        int s = sn[(size_t)n * K_ + tid];
        int f = sf[(size_t)n * K_ + tid];
        const float* p;
        int bs;
        if (s == 0) {                      // source is x
            p  = xbuf + (size_t)f * xfs;
            bs = xbs;
        } else {
            int ls = (s - 1) >> 7;         // source node's layer
            if (ls >= l) {                 // not yet computed -> trace (stop-grad)
                p  = tbuf + (size_t)(s - 1) * SLAB_ + (size_t)f * tfs;
                bs = tbs;
            } else {                       // previously computed output
                p  = obuf + (size_t)(s - 1) * SLAB_ + (size_t)f * ofs;
                bs = obs;
            }
        }
        colp[tid]  = p;
        colbs[tid] = bs;
    }
    __syncthreads();

    // Gather K_ values for this b (coalesced 256 B/instr when bs == 1).
    float g[K_];
#pragma unroll
    for (int k = 0; k < K_; ++k) {
        g[k] = colp[k][(size_t)b * colbs[k]];
    }

    // o[d] = relu(bias[d] + sum_k g[k] * W[d][k]); stage to LDS + write outT.
#pragma unroll
    for (int d = 0; d < D_; ++d) {
        float acc = bsh[d];
#pragma unroll
        for (int k = 0; k < K_; ++k) acc = fmaf(g[k], Wsh[d][k], acc);
        acc = fmaxf(acc, 0.0f);
        osh[tid][d] = acc;
        if (writeT) outT[(size_t)n * SLAB_ + (size_t)d * B_ + b] = acc;  // unit-stride across lanes
    }
    __syncthreads();

    // Native out: block region = out[n, bt*256 .. bt*256+255, :] = 4096 floats
    // contiguous. 4 iterations of 256-thread unit-stride float4 stores.
    float4* region4 = (float4*)(out + (size_t)n * SLAB_ + (size_t)(bt * 256) * D_);
#pragma unroll
    for (int j = 0; j < 4; ++j) {
        int i   = j * 256 + tid;
        int row = i >> 2;
        int c0  = (i & 3) * 4;
        float4 w;
        w.x = osh[row][c0 + 0];
        w.y = osh[row][c0 + 1];
        w.z = osh[row][c0 + 2];
        w.w = osh[row][c0 + 3];
        region4[i] = w;
    }
}

extern "C" void kernel_launch(void* const* d_in, const int* in_sizes, int n_in,
                              void* d_out, int out_size, void* d_ws, size_t ws_size,
                              hipStream_t stream) {
    const float* x     = (const float*)d_in[0];
    const float* trace = (const float*)d_in[1];
    const int*   sn    = (const int*)d_in[2];
    const int*   sf    = (const int*)d_in[3];
    const float* W     = (const float*)d_in[4];
    const float* bias  = (const float*)d_in[5];
    float*       out   = (float*)d_out;

    const size_t xT_elems  = (size_t)D_ * B_;        // 32768
    const size_t big_elems = (size_t)N_ * SLAB_;     // 33554432
    const size_t needA = sizeof(float) * (xT_elems + 2 * big_elems); // ~269 MB
    const size_t needB = sizeof(float) * (xT_elems + 1 * big_elems); // ~134 MB

    float* ws = (float*)d_ws;

    if (ws_size >= needA) {
        // Tier A: fully transposed working set.
        float* xT     = ws;
        float* traceT = ws + xT_elems;
        float* outT   = traceT + big_elems;

        transpose_bd<<<N_ * 32 + 32, 256, 0, stream>>>(trace, x, traceT, xT);
        for (int l = 0; l < L_; ++l) {
            layer_kernel<<<M_ * 8, 256, 0, stream>>>(
                l,
                xT,     B_, 1,
                traceT, B_, 1,
                outT,   B_, 1,
                sn, sf, W, bias, out, outT, 1);
        }
    } else if (ws_size >= needB) {
        // Tier B: transpose x + trace only; outputs gathered from d_out (strided).
        float* xT     = ws;
        float* traceT = ws + xT_elems;

        transpose_bd<<<N_ * 32 + 32, 256, 0, stream>>>(trace, x, traceT, xT);
        for (int l = 0; l < L_; ++l) {
            layer_kernel<<<M_ * 8, 256, 0, stream>>>(
                l,
                xT,     B_, 1,
                traceT, B_, 1,
                out,    1,  D_,
                sn, sf, W, bias, out, nullptr, 0);
        }
    } else {
        // Tier C: no workspace — all native-layout (strided) gathers. Correct, slow.
        for (int l = 0; l < L_; ++l) {
            layer_kernel<<<M_ * 8, 256, 0, stream>>>(
                l,
                x,     1, D_,
                trace, 1, D_,
                out,   1, D_,
                sn, sf, W, bias, out, nullptr, 0);
        }
    }
}